// Round 8
// baseline (205.228 us; speedup 1.0000x reference)
//
#include <hip/hip_runtime.h>
#include <math.h>

// Shapes: B=32, L=128, H=768, E=64, H+E=832, 2H=1536
#define NB 32
#define NL 128
#define NH 768
#define NE 64

// ---------------- ws layout (bytes) ----------------
#define OFF_TOTAL   0         // int g_total (16 B reserved)
#define OFF_NRLIST  16        // int[4096*2] (b,i) pairs            -> 32784
#define OFF_ASLOT   32784     // int[32*128] aspect slot or -1      -> 49168
#define OFF_AIDX    49168     // int[32*4] aspect row index         -> 49680
#define OFF_NASP    49680     // int[32]                            -> 49808
#define OFF_AJCNT   49808     // int[32*4]                          -> 50320
#define OFF_AJIDX   50320     // int[32*4*128]                      -> 115856
#define OFF_SI      115856    // float[4096]                        -> 132240
#define OFF_SJ      132240    // float[4096]                        -> 148624
#define OFF_RMAP    148624    // int[128] zs-row index per (b,slot) -> 149136
#define OFF_VI      149136    // float[768] vi = Wz^T wa_i          -> 152208
#define OFF_VJ      152208    // float[768] vj = Wz^T wa_j          -> 155280
#define OFF_BZD     155280    // float[2] bz.wa_i, bz.wa_j          -> 155296
#define OFF_X2G     155296    // float[128*832]  [y|D]              -> 581280
#define OFF_YB      581280    // float[128*768]  yb = attn@bert_roll-> 974496
#define OFF_ZSA     974496    // float[128*768]  zs at aspect rows  -> 1367712
#define OFF_NBRP    1367712   // float[2*128*768] nbr partials      -> 2154144
#define OFF_TEMPP   2154144   // float[4*128*768] temp partials     -> 3727008

// ---------------- K0: zero the atomic counter (replaces 75us fillBuffer) ----------------
__global__ void k0_zero(int* __restrict__ g_total) { *g_total = 0; }

// ---------------- K1: masks, aspect rows, needed-row compaction ----------------
__global__ __launch_bounds__(128) void k1_masks(
    const int* __restrict__ adj, const int* __restrict__ asp_s, const int* __restrict__ asp_e,
    int* __restrict__ g_total, int* __restrict__ nr_list, int* __restrict__ aspect_slot,
    int* __restrict__ aspect_idx, int* __restrict__ nasp, int* __restrict__ aj_cnt,
    int* __restrict__ aj_idx, int* __restrict__ row_map) {
  int b = blockIdx.x, tid = threadIdx.x;
  __shared__ int asp_flag[128];
  __shared__ int needed[128];
  __shared__ int s_aidx[4];
  __shared__ int s_nasp;
  const int* arow = adj + ((size_t)(b * 128 + tid)) * 128;
  int any = 0;
  for (int j = 0; j < 128; j += 4) {
    int4 v = *(const int4*)(arow + j);
    any |= v.x | v.y | v.z | v.w;
  }
  int s0 = asp_s[b], e0 = asp_e[b];
  int af = (tid >= s0 && tid <= e0 && any > 0) ? 1 : 0;
  asp_flag[tid] = af;
  aspect_slot[b * 128 + tid] = -1;
  __syncthreads();
  if (tid == 0) {
    int n = 0;
    for (int i = 0; i < 128; ++i)
      if (asp_flag[i] && n < 4) s_aidx[n++] = i;
    s_nasp = n;
    nasp[b] = n;
  }
  __syncthreads();
  int na = s_nasp;
  int nd = af;
  for (int s = 0; s < na; ++s) {
    int a = s_aidx[s];
    nd |= (adj[((size_t)(b * 128 + a)) * 128 + tid] > 0) ? 1 : 0;
  }
  needed[tid] = nd;
  if (tid < 4) row_map[b * 4 + tid] = b * 128;  // safe default for invalid slots
  if (tid < na) {
    int a = s_aidx[tid];
    aspect_idx[b * 4 + tid] = a;
    aspect_slot[b * 128 + a] = tid;
    row_map[b * 4 + tid] = b * 128 + a;
    int c = 0;
    const int* ar = adj + ((size_t)(b * 128 + a)) * 128;
    for (int j = 0; j < 128; ++j)
      if (ar[j] > 0) aj_idx[(b * 4 + tid) * 128 + (c++)] = j;
    aj_cnt[b * 4 + tid] = c;
  }
  __syncthreads();
  if (tid == 0) {
    int c = 0;
    for (int i = 0; i < 128; ++i) c += needed[i];
    int base = atomicAdd(g_total, c);
    int k = 0;
    for (int i = 0; i < 128; ++i)
      if (needed[i]) { nr_list[2 * (base + k)] = b; nr_list[2 * (base + k) + 1] = i; ++k; }
  }
}

// ---------------- K1b: vi/vj = Wz^T wa_{i,j}; bzd = (bz.wa_i, bz.wa_j) ----------------
__global__ __launch_bounds__(256) void k1b_proj(
    const float* __restrict__ Wz, const float* __restrict__ wa, const float* __restrict__ bz,
    float* __restrict__ vi, float* __restrict__ vj, float* __restrict__ bzd) {
  int blk = blockIdx.x, tid = threadIdx.x;
  if (blk < 3) {
    int k = blk * 256 + tid;
    float ai = 0.f, aj = 0.f;
#pragma unroll 8
    for (int h = 0; h < 768; ++h) {
      float w = Wz[(size_t)h * 768 + k];  // coalesced across k for fixed h
      ai += w * wa[h];
      aj += w * wa[768 + h];
    }
    vi[k] = ai;
    vj[k] = aj;
  } else {
    if (tid < 64) {
      float bi = 0.f, bj = 0.f;
#pragma unroll
      for (int q = 0; q < 12; ++q) {
        float bv = bz[q * 64 + tid];
        bi += bv * wa[q * 64 + tid];
        bj += bv * wa[768 + q * 64 + tid];
      }
#pragma unroll
      for (int d = 32; d; d >>= 1) { bi += __shfl_xor(bi, d, 64); bj += __shfl_xor(bj, d, 64); }
      if (tid == 0) { bzd[0] = bi; bzd[1] = bj; }
    }
  }
}

// ---------------- K2b: s_i, s_j for needed rows from bert_roll . vi/vj ----------------
__global__ __launch_bounds__(256) void k2b_sij(
    const float* __restrict__ bert, const float* __restrict__ vi, const float* __restrict__ vj,
    const float* __restrict__ bzd,
    const int* __restrict__ g_total, const int* __restrict__ nr_list,
    float* __restrict__ s_i, float* __restrict__ s_j) {
  int gw = (blockIdx.x * 256 + threadIdx.x) >> 6;
  int l = threadIdx.x & 63;
  int total = *g_total;
  for (int s = gw; s < total; s += 256) {
    int b = nr_list[2 * s], i = nr_list[2 * s + 1];
    const float* br = bert + (size_t)(b * 128 + ((i + 1) & 127)) * 768;
    float si = 0.f, sj = 0.f;
#pragma unroll
    for (int q = 0; q < 12; ++q) {
      float v = br[q * 64 + l];
      si += v * vi[q * 64 + l];
      sj += v * vj[q * 64 + l];
    }
#pragma unroll
    for (int d = 32; d; d >>= 1) {
      si += __shfl_xor(si, d, 64);
      sj += __shfl_xor(sj, d, 64);
    }
    if (l == 0) { s_i[b * 128 + i] = si + bzd[0]; s_j[b * 128 + i] = sj + bzd[1]; }
  }
}

// ---------------- K2a: zsa[slot] = bert_roll[aspect row] @ Wz^T + bz (128 rows) ----------------
__global__ __launch_bounds__(128) void k2_zsa(
    const float* __restrict__ bert, const float* __restrict__ Wz, const float* __restrict__ bz,
    const int* __restrict__ row_map, float* __restrict__ zsa) {
  int s0 = blockIdx.x * 4;
  __shared__ float Xs[4][768];
  int tid = threadIdx.x;
  for (int r = 0; r < 4; ++r) {
    int zrow = row_map[s0 + r];
    int bb = zrow >> 7, ii = zrow & 127;
    const float4* src = (const float4*)(bert + ((size_t)(bb * 128) + ((ii + 1) & 127)) * 768);
    for (int q = tid; q < 192; q += 128) ((float4*)Xs[r])[q] = src[q];
  }
  __syncthreads();
  int h = blockIdx.y * 128 + tid;
  const float4* wp = (const float4*)(Wz + (size_t)h * 768);
  float accA[4] = {};
  float accB[4] = {};
#pragma unroll 4
  for (int k4 = 0; k4 < 96; ++k4) {
    float4 w0 = wp[k4];
    float4 w1 = wp[k4 + 96];
#pragma unroll
    for (int r = 0; r < 4; ++r) {
      float4 x0 = ((const float4*)Xs[r])[k4];
      float4 x1 = ((const float4*)Xs[r])[k4 + 96];
      accA[r] += x0.x * w0.x + x0.y * w0.y + x0.z * w0.z + x0.w * w0.w;
      accB[r] += x1.x * w1.x + x1.y * w1.y + x1.z * w1.z + x1.w * w1.w;
    }
  }
  float bzv = bz[h];
#pragma unroll
  for (int r = 0; r < 4; ++r)
    zsa[(size_t)(s0 + r) * 768 + h] = accA[r] + accB[r] + bzv;
}

// ---------------- KA: attention: scores, softmax, yb=attn@bert_roll, D ----------------
__global__ __launch_bounds__(256) void ka_attn(
    const float* __restrict__ dep, const float* __restrict__ bert,
    const float* __restrict__ s_i, const float* __restrict__ s_j,
    const float* __restrict__ wa, const float* __restrict__ ba,
    const int* __restrict__ nasp, const int* __restrict__ aspect_idx,
    const int* __restrict__ aj_cnt, const int* __restrict__ aj_idx,
    float* __restrict__ YB, float* __restrict__ X2g) {
  int b = blockIdx.x;
  int na = nasp[b];
  if (na == 0) return;
  __shared__ float att[4][128];
  __shared__ int jl[4][128];
  __shared__ int aidx[4];
  __shared__ int ajc[4];
  __shared__ float wae[64];
  int tid = threadIdx.x;
  if (tid < 4) { aidx[tid] = aspect_idx[b * 4 + tid]; ajc[tid] = aj_cnt[b * 4 + tid]; }
  if (tid < 64) wae[tid] = wa[1536 + tid];
  for (int q = tid; q < 512; q += 256) jl[q >> 7][q & 127] = aj_idx[b * 512 + q];
  __syncthreads();
  int w = tid >> 6, l = tid & 63;
  if (w >= na) return;
  int a = aidx[w], cj = ajc[w];
  float sib = s_i[b * 128 + a] + ba[0];
  const float* depa = dep + ((size_t)(b * 128 + a)) * 128 * 64;
  float sc0 = -INFINITY, sc1 = -INFINITY;
  for (int t = l; t < cj; t += 64) {
    int j = jl[w][t];
    const float4* dp = (const float4*)(depa + (size_t)j * 64);
    float se = 0.f;
#pragma unroll
    for (int q = 0; q < 16; ++q) {
      float4 v = dp[q];
      se += v.x * wae[4 * q] + v.y * wae[4 * q + 1] + v.z * wae[4 * q + 2] + v.w * wae[4 * q + 3];
    }
    float sc = sib + s_j[b * 128 + j] + se;
    sc = (sc >= 0.f) ? sc : 0.01f * sc;
    if (t < 64) sc0 = sc; else sc1 = sc;
  }
  float mx = fmaxf(sc0, sc1);
#pragma unroll
  for (int d = 32; d; d >>= 1) mx = fmaxf(mx, __shfl_xor(mx, d, 64));
  float p0 = expf(sc0 - mx), p1 = expf(sc1 - mx);
  float sm = p0 + p1;
#pragma unroll
  for (int d = 32; d; d >>= 1) sm += __shfl_xor(sm, d, 64);
  float inv = 1.f / sm;
  if (l < cj) att[w][l] = p0 * inv;
  if (l + 64 < cj) att[w][l + 64] = p1 * inv;
  // yb = attn @ bert_roll (12 regs/lane), D = attn @ dep_row
  float y[12];
#pragma unroll
  for (int q = 0; q < 12; ++q) y[q] = 0.f;
  float dacc = 0.f;
  for (int t = 0; t < cj; ++t) {
    float at = att[w][t];
    int j = jl[w][t];
    const float* br = bert + (size_t)(b * 128 + ((j + 1) & 127)) * 768;
#pragma unroll
    for (int q = 0; q < 12; ++q) y[q] += at * br[q * 64 + l];
    dacc += at * depa[(size_t)j * 64 + l];
  }
  float* yr = YB + (size_t)(b * 4 + w) * 768;
#pragma unroll
  for (int q = 0; q < 12; ++q) yr[q * 64 + l] = y[q];
  X2g[(size_t)(b * 4 + w) * 832 + 768 + l] = dacc;
}

// ---------------- G0: X2g.y = YB @ Wz^T + bz (128 rows) ----------------
__global__ __launch_bounds__(128) void g0_wz(
    const float* __restrict__ YB, const float* __restrict__ Wz, const float* __restrict__ bz,
    float* __restrict__ X2g) {
  int s0 = blockIdx.x * 4;
  __shared__ float Xs[4][768];
  int tid = threadIdx.x;
  for (int r = 0; r < 4; ++r) {
    const float4* src = (const float4*)(YB + (size_t)(s0 + r) * 768);
    for (int q = tid; q < 192; q += 128) ((float4*)Xs[r])[q] = src[q];
  }
  __syncthreads();
  int h = blockIdx.y * 128 + tid;
  const float4* wp = (const float4*)(Wz + (size_t)h * 768);
  float accA[4] = {};
  float accB[4] = {};
#pragma unroll 4
  for (int k4 = 0; k4 < 96; ++k4) {
    float4 w0 = wp[k4];
    float4 w1 = wp[k4 + 96];
#pragma unroll
    for (int r = 0; r < 4; ++r) {
      float4 x0 = ((const float4*)Xs[r])[k4];
      float4 x1 = ((const float4*)Xs[r])[k4 + 96];
      accA[r] += x0.x * w0.x + x0.y * w0.y + x0.z * w0.z + x0.w * w0.w;
      accB[r] += x1.x * w1.x + x1.y * w1.y + x1.z * w1.z + x1.w * w1.w;
    }
  }
  float bzv = bz[h];
#pragma unroll
  for (int r = 0; r < 4; ++r)
    X2g[(size_t)(s0 + r) * 832 + h] = accA[r] + accB[r] + bzv;
}

// ---------------- G1: nbr partials = X2g @ Wf^T (K=832, 2 chunks) ----------------
__global__ __launch_bounds__(256) void gemv1_wf(
    const float* __restrict__ X2g, const float* __restrict__ Wf,
    float* __restrict__ nbr_part) {
  int g = blockIdx.x, nc = blockIdx.y, kc = blockIdx.z;
  int tid = threadIdx.x;
  __shared__ float Xs[4][416];
#pragma unroll
  for (int r = 0; r < 4; ++r) {
    if (tid < 104)
      ((float4*)Xs[r])[tid] = *((const float4*)(X2g + (size_t)(g * 4 + r) * 832 + kc * 416) + tid);
  }
  __syncthreads();
  int h = nc * 256 + tid;
  float acc[4] = {};
  const float4* wp = (const float4*)(Wf + (size_t)h * 832 + kc * 416);
#pragma unroll 4
  for (int k4 = 0; k4 < 104; ++k4) {
    float4 wv = wp[k4];
#pragma unroll
    for (int r = 0; r < 4; ++r) {
      float4 xv = ((const float4*)Xs[r])[k4];
      acc[r] += xv.x * wv.x + xv.y * wv.y + xv.z * wv.z + xv.w * wv.w;
    }
  }
#pragma unroll
  for (int r = 0; r < 4; ++r)
    nbr_part[((size_t)kc * 128 + g * 4 + r) * 768 + h] = acc[r];
}

// ---------------- G2: temp partials = [nbr|zsa] @ Wh^T (K=1536, 4 chunks) ----------------
__global__ __launch_bounds__(256) void gemv2_wh(
    const float* __restrict__ nbr_part, const float* __restrict__ zsa,
    const float* __restrict__ Wh, float* __restrict__ temp_part) {
  int g = blockIdx.x, nc = blockIdx.y, kc = blockIdx.z;
  int tid = threadIdx.x;
  __shared__ float Xs[4][384];
  if (kc < 2) {  // nbr half: sum the two K-partials
#pragma unroll
    for (int r = 0; r < 4; ++r) {
      if (tid < 96) {
        int row = g * 4 + r;
        float4 p0 = *((const float4*)(nbr_part + (size_t)row * 768 + kc * 384) + tid);
        float4 p1 = *((const float4*)(nbr_part + ((size_t)128 + row) * 768 + kc * 384) + tid);
        ((float4*)Xs[r])[tid] = make_float4(p0.x + p1.x, p0.y + p1.y, p0.z + p1.z, p0.w + p1.w);
      }
    }
  } else {  // zsa half (compact slot rows)
#pragma unroll
    for (int r = 0; r < 4; ++r) {
      if (tid < 96)
        ((float4*)Xs[r])[tid] = *((const float4*)(zsa + (size_t)(g * 4 + r) * 768 + (kc - 2) * 384) + tid);
    }
  }
  __syncthreads();
  int h = nc * 256 + tid;
  float acc[4] = {};
  const float4* wp = (const float4*)(Wh + (size_t)h * 1536 + kc * 384);
#pragma unroll 4
  for (int k4 = 0; k4 < 96; ++k4) {
    float4 wv = wp[k4];
#pragma unroll
    for (int r = 0; r < 4; ++r) {
      float4 xv = ((const float4*)Xs[r])[k4];
      acc[r] += xv.x * wv.x + xv.y * wv.y + xv.z * wv.z + xv.w * wv.w;
    }
  }
#pragma unroll
  for (int r = 0; r < 4; ++r)
    temp_part[((size_t)kc * 128 + g * 4 + r) * 768 + h] = acc[r];
}

// ---------------- K4: out = upd[i-1] ? sum(temp_part)[i-1] : bert[i] ----------------
__global__ __launch_bounds__(256) void k4_out(
    const float* __restrict__ bert, const float* __restrict__ temp_part,
    const int* __restrict__ aspect_slot, float* __restrict__ out) {
  int idx = blockIdx.x * 256 + threadIdx.x;  // float4 index
  if (idx >= NB * NL * NH / 4) return;
  int row = idx / 192;  // 192 float4 per row
  int c4 = idx - row * 192;
  int b = row >> 7, i = row & 127;
  int slot = -1;
  if (i > 0) slot = aspect_slot[b * 128 + i - 1];
  float4 v;
  if (slot >= 0) {
    int trow = b * 4 + slot;
    float4 a0 = *((const float4*)(temp_part + (size_t)trow * 768) + c4);
    float4 a1 = *((const float4*)(temp_part + ((size_t)128 + trow) * 768) + c4);
    float4 a2 = *((const float4*)(temp_part + ((size_t)256 + trow) * 768) + c4);
    float4 a3 = *((const float4*)(temp_part + ((size_t)384 + trow) * 768) + c4);
    v = make_float4(a0.x + a1.x + a2.x + a3.x, a0.y + a1.y + a2.y + a3.y,
                    a0.z + a1.z + a2.z + a3.z, a0.w + a1.w + a2.w + a3.w);
  } else {
    v = *(const float4*)(bert + (size_t)row * 768 + c4 * 4);
  }
  *((float4*)out + idx) = v;
}

extern "C" void kernel_launch(void* const* d_in, const int* in_sizes, int n_in,
                              void* d_out, int out_size, void* d_ws, size_t ws_size,
                              hipStream_t stream) {
  const float* bert = (const float*)d_in[0];
  const float* dep  = (const float*)d_in[1];
  const int*   adj  = (const int*)d_in[2];
  const int*   asps = (const int*)d_in[3];
  const int*   aspe = (const int*)d_in[4];
  const float* Wz   = (const float*)d_in[5];
  const float* bz   = (const float*)d_in[6];
  const float* wa   = (const float*)d_in[7];
  const float* ba   = (const float*)d_in[8];
  const float* Wf   = (const float*)d_in[9];
  const float* Wh   = (const float*)d_in[10];
  float* out = (float*)d_out;
  char* ws = (char*)d_ws;

  int*   g_total     = (int*)(ws + OFF_TOTAL);
  int*   nr_list     = (int*)(ws + OFF_NRLIST);
  int*   aspect_slot = (int*)(ws + OFF_ASLOT);
  int*   aspect_idx  = (int*)(ws + OFF_AIDX);
  int*   nasp        = (int*)(ws + OFF_NASP);
  int*   aj_cnt      = (int*)(ws + OFF_AJCNT);
  int*   aj_idx      = (int*)(ws + OFF_AJIDX);
  float* s_i         = (float*)(ws + OFF_SI);
  float* s_j         = (float*)(ws + OFF_SJ);
  int*   row_map     = (int*)(ws + OFF_RMAP);
  float* vi          = (float*)(ws + OFF_VI);
  float* vj          = (float*)(ws + OFF_VJ);
  float* bzd         = (float*)(ws + OFF_BZD);
  float* X2g         = (float*)(ws + OFF_X2G);
  float* YB          = (float*)(ws + OFF_YB);
  float* zsa         = (float*)(ws + OFF_ZSA);
  float* nbr_part    = (float*)(ws + OFF_NBRP);
  float* temp_part   = (float*)(ws + OFF_TEMPP);

  k0_zero<<<1, 1, 0, stream>>>(g_total);
  k1_masks<<<NB, 128, 0, stream>>>(adj, asps, aspe, g_total, nr_list, aspect_slot,
                                   aspect_idx, nasp, aj_cnt, aj_idx, row_map);
  k1b_proj<<<4, 256, 0, stream>>>(Wz, wa, bz, vi, vj, bzd);
  k2b_sij<<<64, 256, 0, stream>>>(bert, vi, vj, bzd, g_total, nr_list, s_i, s_j);
  k2_zsa<<<dim3(32, 6), 128, 0, stream>>>(bert, Wz, bz, row_map, zsa);
  ka_attn<<<NB, 256, 0, stream>>>(dep, bert, s_i, s_j, wa, ba,
                                  nasp, aspect_idx, aj_cnt, aj_idx, YB, X2g);
  g0_wz<<<dim3(32, 6), 128, 0, stream>>>(YB, Wz, bz, X2g);
  gemv1_wf<<<dim3(32, 3, 2), 256, 0, stream>>>(X2g, Wf, nbr_part);
  gemv2_wh<<<dim3(32, 3, 4), 256, 0, stream>>>(nbr_part, zsa, Wh, temp_part);
  k4_out<<<(NB * NL * NH / 4 + 255) / 256, 256, 0, stream>>>(bert, temp_part, aspect_slot, out);
}

// Round 9
// 175.084 us; speedup vs baseline: 1.1722x; 1.1722x over previous
//
#include <hip/hip_runtime.h>
#include <math.h>

// Shapes: B=32, L=128, H=768, E=64, H+E=832, 2H=1536
#define NB 32
#define NL 128
#define NH 768
#define NE 64

// ---------------- ws layout (bytes) ----------------
#define OFF_TOTAL   0         // int g_total
#define OFF_NRLIST  16        // int[4096*2]                        -> 32784
#define OFF_ASLOT   32784     // int[32*128]                        -> 49168
#define OFF_AIDX    49168     // int[32*4]                          -> 49680
#define OFF_NASP    49680     // int[32]                            -> 49808
#define OFF_AJCNT   49808     // int[32*4]                          -> 50320
#define OFF_AJIDX   50320     // int[32*4*128]                      -> 115856
#define OFF_SI      115856    // float[4096]                        -> 132240
#define OFF_SJ      132240    // float[4096]                        -> 148624
#define OFF_RMAP    148624    // int[128]                           -> 149136
#define OFF_VI      149136    // float[768]                         -> 152208
#define OFF_VJ      152208    // float[768]                         -> 155280
#define OFF_BZD     155280    // float[2]                           -> 155296
#define OFF_YB      155296    // float[128*768] yb=attn@bert_roll   -> 548512
#define OFF_DG      548512    // float[128*64]  D                   -> 581280
#define OFF_YP      581280    // float[4*128*768] y partials        -> 2154144
#define OFF_ZSAP    2154144   // float[4*128*768] zsa partials      -> 3727008
#define OFF_NBRP    3727008   // float[2*128*768] nbr partials      -> 4513440
#define OFF_TEMPP   4513440   // float[4*128*768] temp partials     -> 6086304

// ---------------- K1b: vi/vj = Wz^T wa_{i,j}; bzd; zero g_total ----------------
__global__ __launch_bounds__(256) void k1b_proj(
    const float* __restrict__ Wz, const float* __restrict__ wa, const float* __restrict__ bz,
    float* __restrict__ vi, float* __restrict__ vj, float* __restrict__ bzd,
    int* __restrict__ g_total) {
  int blk = blockIdx.x, tid = threadIdx.x;
  if (blk < 3) {
    int k = blk * 256 + tid;
    float ai = 0.f, aj = 0.f;
#pragma unroll 8
    for (int h = 0; h < 768; ++h) {
      float w = Wz[(size_t)h * 768 + k];
      ai += w * wa[h];
      aj += w * wa[768 + h];
    }
    vi[k] = ai;
    vj[k] = aj;
  } else {
    if (tid == 64) *g_total = 0;
    if (tid < 64) {
      float bi = 0.f, bj = 0.f;
#pragma unroll
      for (int q = 0; q < 12; ++q) {
        float bv = bz[q * 64 + tid];
        bi += bv * wa[q * 64 + tid];
        bj += bv * wa[768 + q * 64 + tid];
      }
#pragma unroll
      for (int d = 32; d; d >>= 1) { bi += __shfl_xor(bi, d, 64); bj += __shfl_xor(bj, d, 64); }
      if (tid == 0) { bzd[0] = bi; bzd[1] = bj; }
    }
  }
}

// ---------------- K1: masks, aspect rows, needed-row compaction ----------------
__global__ __launch_bounds__(128) void k1_masks(
    const int* __restrict__ adj, const int* __restrict__ asp_s, const int* __restrict__ asp_e,
    int* __restrict__ g_total, int* __restrict__ nr_list, int* __restrict__ aspect_slot,
    int* __restrict__ aspect_idx, int* __restrict__ nasp, int* __restrict__ aj_cnt,
    int* __restrict__ aj_idx, int* __restrict__ row_map) {
  int b = blockIdx.x, tid = threadIdx.x;
  __shared__ int asp_flag[128];
  __shared__ int needed[128];
  __shared__ int s_aidx[4];
  __shared__ int s_nasp;
  const int* arow = adj + ((size_t)(b * 128 + tid)) * 128;
  int any = 0;
  for (int j = 0; j < 128; j += 4) {
    int4 v = *(const int4*)(arow + j);
    any |= v.x | v.y | v.z | v.w;
  }
  int s0 = asp_s[b], e0 = asp_e[b];
  int af = (tid >= s0 && tid <= e0 && any > 0) ? 1 : 0;
  asp_flag[tid] = af;
  aspect_slot[b * 128 + tid] = -1;
  __syncthreads();
  if (tid == 0) {
    int n = 0;
    for (int i = 0; i < 128; ++i)
      if (asp_flag[i] && n < 4) s_aidx[n++] = i;
    s_nasp = n;
    nasp[b] = n;
  }
  __syncthreads();
  int na = s_nasp;
  int nd = af;
  for (int s = 0; s < na; ++s) {
    int a = s_aidx[s];
    nd |= (adj[((size_t)(b * 128 + a)) * 128 + tid] > 0) ? 1 : 0;
  }
  needed[tid] = nd;
  if (tid < 4) row_map[b * 4 + tid] = b * 128;
  if (tid < na) {
    int a = s_aidx[tid];
    aspect_idx[b * 4 + tid] = a;
    aspect_slot[b * 128 + a] = tid;
    row_map[b * 4 + tid] = b * 128 + a;
    int c = 0;
    const int* ar = adj + ((size_t)(b * 128 + a)) * 128;
    for (int j = 0; j < 128; ++j)
      if (ar[j] > 0) aj_idx[(b * 4 + tid) * 128 + (c++)] = j;
    aj_cnt[b * 4 + tid] = c;
  }
  __syncthreads();
  if (tid == 0) {
    int c = 0;
    for (int i = 0; i < 128; ++i) c += needed[i];
    int base = atomicAdd(g_total, c);
    int k = 0;
    for (int i = 0; i < 128; ++i)
      if (needed[i]) { nr_list[2 * (base + k)] = b; nr_list[2 * (base + k) + 1] = i; ++k; }
  }
}

// ---------------- K2b: s_i, s_j for needed rows ----------------
__global__ __launch_bounds__(256) void k2b_sij(
    const float* __restrict__ bert, const float* __restrict__ vi, const float* __restrict__ vj,
    const float* __restrict__ bzd,
    const int* __restrict__ g_total, const int* __restrict__ nr_list,
    float* __restrict__ s_i, float* __restrict__ s_j) {
  int gw = (blockIdx.x * 256 + threadIdx.x) >> 6;
  int l = threadIdx.x & 63;
  int total = *g_total;
  for (int s = gw; s < total; s += 256) {
    int b = nr_list[2 * s], i = nr_list[2 * s + 1];
    const float* br = bert + (size_t)(b * 128 + ((i + 1) & 127)) * 768;
    float si = 0.f, sj = 0.f;
#pragma unroll
    for (int q = 0; q < 12; ++q) {
      float v = br[q * 64 + l];
      si += v * vi[q * 64 + l];
      sj += v * vj[q * 64 + l];
    }
#pragma unroll
    for (int d = 32; d; d >>= 1) {
      si += __shfl_xor(si, d, 64);
      sj += __shfl_xor(sj, d, 64);
    }
    if (l == 0) { s_i[b * 128 + i] = si + bzd[0]; s_j[b * 128 + i] = sj + bzd[1]; }
  }
}

// ---------------- K2a: zsa partials, K-split by 4 ----------------
// grid (32, 6, 4), block 128: rows s0=bx*4, h=by*128+tid, K-chunk kc*192.
__global__ __launch_bounds__(128) void k2_zsa(
    const float* __restrict__ bert, const float* __restrict__ Wz, const float* __restrict__ bz,
    const int* __restrict__ row_map, float* __restrict__ zsap) {
  int s0 = blockIdx.x * 4, kc = blockIdx.z;
  __shared__ float Xs[4][192];
  int tid = threadIdx.x;
  for (int q = tid; q < 192; q += 128) {
    int r = q / 48, c = q - r * 48;
    int zrow = row_map[s0 + r];
    int bb = zrow >> 7, ii = zrow & 127;
    const float4* src = (const float4*)(bert + ((size_t)(bb * 128) + ((ii + 1) & 127)) * 768) + kc * 48;
    ((float4*)Xs[r])[c] = src[c];
  }
  __syncthreads();
  int h = blockIdx.y * 128 + tid;
  const float4* wp = (const float4*)(Wz + (size_t)h * 768) + kc * 48;
  float accA[4] = {};
  float accB[4] = {};
#pragma unroll 6
  for (int k4 = 0; k4 < 24; ++k4) {
    float4 w0 = wp[k4];
    float4 w1 = wp[k4 + 24];
#pragma unroll
    for (int r = 0; r < 4; ++r) {
      float4 x0 = ((const float4*)Xs[r])[k4];
      float4 x1 = ((const float4*)Xs[r])[k4 + 24];
      accA[r] += x0.x * w0.x + x0.y * w0.y + x0.z * w0.z + x0.w * w0.w;
      accB[r] += x1.x * w1.x + x1.y * w1.y + x1.z * w1.z + x1.w * w1.w;
    }
  }
  float bzv = (kc == 0) ? bz[h] : 0.f;
#pragma unroll
  for (int r = 0; r < 4; ++r)
    zsap[((size_t)kc * 128 + s0 + r) * 768 + h] = accA[r] + accB[r] + bzv;
}

// ---------------- KA: attention: scores, softmax, yb=attn@bert_roll, D ----------------
__global__ __launch_bounds__(256) void ka_attn(
    const float* __restrict__ dep, const float* __restrict__ bert,
    const float* __restrict__ s_i, const float* __restrict__ s_j,
    const float* __restrict__ wa, const float* __restrict__ ba,
    const int* __restrict__ nasp, const int* __restrict__ aspect_idx,
    const int* __restrict__ aj_cnt, const int* __restrict__ aj_idx,
    float* __restrict__ YB, float* __restrict__ DG) {
  int b = blockIdx.x;
  int na = nasp[b];
  if (na == 0) return;
  __shared__ float att[4][128];
  __shared__ int jl[4][128];
  __shared__ int aidx[4];
  __shared__ int ajc[4];
  __shared__ float wae[64];
  int tid = threadIdx.x;
  if (tid < 4) { aidx[tid] = aspect_idx[b * 4 + tid]; ajc[tid] = aj_cnt[b * 4 + tid]; }
  if (tid < 64) wae[tid] = wa[1536 + tid];
  for (int q = tid; q < 512; q += 256) jl[q >> 7][q & 127] = aj_idx[b * 512 + q];
  __syncthreads();
  int w = tid >> 6, l = tid & 63;
  if (w >= na) return;
  int a = aidx[w], cj = ajc[w];
  float sib = s_i[b * 128 + a] + ba[0];
  const float* depa = dep + ((size_t)(b * 128 + a)) * 128 * 64;
  float sc0 = -INFINITY, sc1 = -INFINITY;
  for (int t = l; t < cj; t += 64) {
    int j = jl[w][t];
    const float4* dp = (const float4*)(depa + (size_t)j * 64);
    float se = 0.f;
#pragma unroll
    for (int q = 0; q < 16; ++q) {
      float4 v = dp[q];
      se += v.x * wae[4 * q] + v.y * wae[4 * q + 1] + v.z * wae[4 * q + 2] + v.w * wae[4 * q + 3];
    }
    float sc = sib + s_j[b * 128 + j] + se;
    sc = (sc >= 0.f) ? sc : 0.01f * sc;
    if (t < 64) sc0 = sc; else sc1 = sc;
  }
  float mx = fmaxf(sc0, sc1);
#pragma unroll
  for (int d = 32; d; d >>= 1) mx = fmaxf(mx, __shfl_xor(mx, d, 64));
  float p0 = expf(sc0 - mx), p1 = expf(sc1 - mx);
  float sm = p0 + p1;
#pragma unroll
  for (int d = 32; d; d >>= 1) sm += __shfl_xor(sm, d, 64);
  float inv = 1.f / sm;
  if (l < cj) att[w][l] = p0 * inv;
  if (l + 64 < cj) att[w][l + 64] = p1 * inv;
  float y[12];
#pragma unroll
  for (int q = 0; q < 12; ++q) y[q] = 0.f;
  float dacc = 0.f;
  for (int t = 0; t < cj; ++t) {
    float at = att[w][t];
    int j = jl[w][t];
    const float* br = bert + (size_t)(b * 128 + ((j + 1) & 127)) * 768;
#pragma unroll
    for (int q = 0; q < 12; ++q) y[q] += at * br[q * 64 + l];
    dacc += at * depa[(size_t)j * 64 + l];
  }
  float* yr = YB + (size_t)(b * 4 + w) * 768;
#pragma unroll
  for (int q = 0; q < 12; ++q) yr[q * 64 + l] = y[q];
  DG[(b * 4 + w) * 64 + l] = dacc;
}

// ---------------- G0: y partials = YB @ Wz^T + bz, K-split by 4 ----------------
__global__ __launch_bounds__(128) void g0_wz(
    const float* __restrict__ YB, const float* __restrict__ Wz, const float* __restrict__ bz,
    float* __restrict__ yp) {
  int s0 = blockIdx.x * 4, kc = blockIdx.z;
  __shared__ float Xs[4][192];
  int tid = threadIdx.x;
  for (int q = tid; q < 192; q += 128) {
    int r = q / 48, c = q - r * 48;
    const float4* src = (const float4*)(YB + (size_t)(s0 + r) * 768) + kc * 48;
    ((float4*)Xs[r])[c] = src[c];
  }
  __syncthreads();
  int h = blockIdx.y * 128 + tid;
  const float4* wp = (const float4*)(Wz + (size_t)h * 768) + kc * 48;
  float accA[4] = {};
  float accB[4] = {};
#pragma unroll 6
  for (int k4 = 0; k4 < 24; ++k4) {
    float4 w0 = wp[k4];
    float4 w1 = wp[k4 + 24];
#pragma unroll
    for (int r = 0; r < 4; ++r) {
      float4 x0 = ((const float4*)Xs[r])[k4];
      float4 x1 = ((const float4*)Xs[r])[k4 + 24];
      accA[r] += x0.x * w0.x + x0.y * w0.y + x0.z * w0.z + x0.w * w0.w;
      accB[r] += x1.x * w1.x + x1.y * w1.y + x1.z * w1.z + x1.w * w1.w;
    }
  }
  float bzv = (kc == 0) ? bz[h] : 0.f;
#pragma unroll
  for (int r = 0; r < 4; ++r)
    yp[((size_t)kc * 128 + s0 + r) * 768 + h] = accA[r] + accB[r] + bzv;
}

// ---------------- G1: nbr partials = [y|D] @ Wf^T (K=832, 2 chunks) ----------------
__global__ __launch_bounds__(256) void gemv1_wf(
    const float* __restrict__ yp, const float* __restrict__ DG, const float* __restrict__ Wf,
    float* __restrict__ nbr_part) {
  int g = blockIdx.x, nc = blockIdx.y, kc = blockIdx.z;
  int tid = threadIdx.x;
  __shared__ float Xs[4][416];
#pragma unroll
  for (int r = 0; r < 4; ++r) {
    if (tid < 104) {
      int row = g * 4 + r;
      int Q = kc * 104 + tid;  // global f4 index in [y(192 f4)|D(16 f4)]
      float4 v;
      if (Q < 192) {
        float4 p0 = *((const float4*)(yp + (size_t)row * 768) + Q);
        float4 p1 = *((const float4*)(yp + ((size_t)128 + row) * 768) + Q);
        float4 p2 = *((const float4*)(yp + ((size_t)256 + row) * 768) + Q);
        float4 p3 = *((const float4*)(yp + ((size_t)384 + row) * 768) + Q);
        v = make_float4(p0.x + p1.x + p2.x + p3.x, p0.y + p1.y + p2.y + p3.y,
                        p0.z + p1.z + p2.z + p3.z, p0.w + p1.w + p2.w + p3.w);
      } else {
        v = *((const float4*)(DG + (size_t)row * 64) + (Q - 192));
      }
      ((float4*)Xs[r])[tid] = v;
    }
  }
  __syncthreads();
  int h = nc * 256 + tid;
  float acc[4] = {};
  const float4* wp = (const float4*)(Wf + (size_t)h * 832 + kc * 416);
#pragma unroll 4
  for (int k4 = 0; k4 < 104; ++k4) {
    float4 wv = wp[k4];
#pragma unroll
    for (int r = 0; r < 4; ++r) {
      float4 xv = ((const float4*)Xs[r])[k4];
      acc[r] += xv.x * wv.x + xv.y * wv.y + xv.z * wv.z + xv.w * wv.w;
    }
  }
#pragma unroll
  for (int r = 0; r < 4; ++r)
    nbr_part[((size_t)kc * 128 + g * 4 + r) * 768 + h] = acc[r];
}

// ---------------- G2: temp partials = [nbr|zsa] @ Wh^T (K=1536, 4 chunks) ----------------
__global__ __launch_bounds__(256) void gemv2_wh(
    const float* __restrict__ nbr_part, const float* __restrict__ zsap,
    const float* __restrict__ Wh, float* __restrict__ temp_part) {
  int g = blockIdx.x, nc = blockIdx.y, kc = blockIdx.z;
  int tid = threadIdx.x;
  __shared__ float Xs[4][384];
  if (kc < 2) {  // nbr half: sum the two K-partials
#pragma unroll
    for (int r = 0; r < 4; ++r) {
      if (tid < 96) {
        int row = g * 4 + r;
        float4 p0 = *((const float4*)(nbr_part + (size_t)row * 768 + kc * 384) + tid);
        float4 p1 = *((const float4*)(nbr_part + ((size_t)128 + row) * 768 + kc * 384) + tid);
        ((float4*)Xs[r])[tid] = make_float4(p0.x + p1.x, p0.y + p1.y, p0.z + p1.z, p0.w + p1.w);
      }
    }
  } else {  // zsa half: sum 4 K-partials
#pragma unroll
    for (int r = 0; r < 4; ++r) {
      if (tid < 96) {
        int row = g * 4 + r;
        int Q = (kc - 2) * 96 + tid;
        float4 p0 = *((const float4*)(zsap + (size_t)row * 768) + Q);
        float4 p1 = *((const float4*)(zsap + ((size_t)128 + row) * 768) + Q);
        float4 p2 = *((const float4*)(zsap + ((size_t)256 + row) * 768) + Q);
        float4 p3 = *((const float4*)(zsap + ((size_t)384 + row) * 768) + Q);
        ((float4*)Xs[r])[tid] = make_float4(p0.x + p1.x + p2.x + p3.x, p0.y + p1.y + p2.y + p3.y,
                                            p0.z + p1.z + p2.z + p3.z, p0.w + p1.w + p2.w + p3.w);
      }
    }
  }
  __syncthreads();
  int h = nc * 256 + tid;
  float acc[4] = {};
  const float4* wp = (const float4*)(Wh + (size_t)h * 1536 + kc * 384);
#pragma unroll 4
  for (int k4 = 0; k4 < 96; ++k4) {
    float4 wv = wp[k4];
#pragma unroll
    for (int r = 0; r < 4; ++r) {
      float4 xv = ((const float4*)Xs[r])[k4];
      acc[r] += xv.x * wv.x + xv.y * wv.y + xv.z * wv.z + xv.w * wv.w;
    }
  }
#pragma unroll
  for (int r = 0; r < 4; ++r)
    temp_part[((size_t)kc * 128 + g * 4 + r) * 768 + h] = acc[r];
}

// ---------------- K4: out = upd[i-1] ? sum(temp_part)[i-1] : bert[i] ----------------
__global__ __launch_bounds__(256) void k4_out(
    const float* __restrict__ bert, const float* __restrict__ temp_part,
    const int* __restrict__ aspect_slot, float* __restrict__ out) {
  int idx = blockIdx.x * 256 + threadIdx.x;
  if (idx >= NB * NL * NH / 4) return;
  int row = idx / 192;
  int c4 = idx - row * 192;
  int b = row >> 7, i = row & 127;
  int slot = -1;
  if (i > 0) slot = aspect_slot[b * 128 + i - 1];
  float4 v;
  if (slot >= 0) {
    int trow = b * 4 + slot;
    float4 a0 = *((const float4*)(temp_part + (size_t)trow * 768) + c4);
    float4 a1 = *((const float4*)(temp_part + ((size_t)128 + trow) * 768) + c4);
    float4 a2 = *((const float4*)(temp_part + ((size_t)256 + trow) * 768) + c4);
    float4 a3 = *((const float4*)(temp_part + ((size_t)384 + trow) * 768) + c4);
    v = make_float4(a0.x + a1.x + a2.x + a3.x, a0.y + a1.y + a2.y + a3.y,
                    a0.z + a1.z + a2.z + a3.z, a0.w + a1.w + a2.w + a3.w);
  } else {
    v = *(const float4*)(bert + (size_t)row * 768 + c4 * 4);
  }
  *((float4*)out + idx) = v;
}

extern "C" void kernel_launch(void* const* d_in, const int* in_sizes, int n_in,
                              void* d_out, int out_size, void* d_ws, size_t ws_size,
                              hipStream_t stream) {
  const float* bert = (const float*)d_in[0];
  const float* dep  = (const float*)d_in[1];
  const int*   adj  = (const int*)d_in[2];
  const int*   asps = (const int*)d_in[3];
  const int*   aspe = (const int*)d_in[4];
  const float* Wz   = (const float*)d_in[5];
  const float* bz   = (const float*)d_in[6];
  const float* wa   = (const float*)d_in[7];
  const float* ba   = (const float*)d_in[8];
  const float* Wf   = (const float*)d_in[9];
  const float* Wh   = (const float*)d_in[10];
  float* out = (float*)d_out;
  char* ws = (char*)d_ws;

  int*   g_total     = (int*)(ws + OFF_TOTAL);
  int*   nr_list     = (int*)(ws + OFF_NRLIST);
  int*   aspect_slot = (int*)(ws + OFF_ASLOT);
  int*   aspect_idx  = (int*)(ws + OFF_AIDX);
  int*   nasp        = (int*)(ws + OFF_NASP);
  int*   aj_cnt      = (int*)(ws + OFF_AJCNT);
  int*   aj_idx      = (int*)(ws + OFF_AJIDX);
  float* s_i         = (float*)(ws + OFF_SI);
  float* s_j         = (float*)(ws + OFF_SJ);
  int*   row_map     = (int*)(ws + OFF_RMAP);
  float* vi          = (float*)(ws + OFF_VI);
  float* vj          = (float*)(ws + OFF_VJ);
  float* bzd         = (float*)(ws + OFF_BZD);
  float* YB          = (float*)(ws + OFF_YB);
  float* DG          = (float*)(ws + OFF_DG);
  float* yp          = (float*)(ws + OFF_YP);
  float* zsap        = (float*)(ws + OFF_ZSAP);
  float* nbr_part    = (float*)(ws + OFF_NBRP);
  float* temp_part   = (float*)(ws + OFF_TEMPP);

  k1b_proj<<<4, 256, 0, stream>>>(Wz, wa, bz, vi, vj, bzd, g_total);
  k1_masks<<<NB, 128, 0, stream>>>(adj, asps, aspe, g_total, nr_list, aspect_slot,
                                   aspect_idx, nasp, aj_cnt, aj_idx, row_map);
  k2b_sij<<<64, 256, 0, stream>>>(bert, vi, vj, bzd, g_total, nr_list, s_i, s_j);
  k2_zsa<<<dim3(32, 6, 4), 128, 0, stream>>>(bert, Wz, bz, row_map, zsap);
  ka_attn<<<NB, 256, 0, stream>>>(dep, bert, s_i, s_j, wa, ba,
                                  nasp, aspect_idx, aj_cnt, aj_idx, YB, DG);
  g0_wz<<<dim3(32, 6, 4), 128, 0, stream>>>(YB, Wz, bz, yp);
  gemv1_wf<<<dim3(32, 3, 2), 256, 0, stream>>>(yp, DG, Wf, nbr_part);
  gemv2_wh<<<dim3(32, 3, 4), 256, 0, stream>>>(nbr_part, zsap, Wh, temp_part);
  k4_out<<<(NB * NL * NH / 4 + 255) / 256, 256, 0, stream>>>(bert, temp_part, aspect_slot, out);
}

// Round 10
// 135.190 us; speedup vs baseline: 1.5181x; 1.2951x over previous
//
#include <hip/hip_runtime.h>
#include <math.h>

// Shapes: B=32, L=128, H=768, E=64, H+E=832, 2H=1536
#define NB 32
#define NL 128
#define NH 768
#define NE 64

// ---------------- ws layout (bytes) ----------------
#define OFF_ASLOT   32784     // int[32*128] aspect slot or -1      -> 49168
#define OFF_AIDX    49168     // int[32*4]                          -> 49680
#define OFF_NASP    49680     // int[32]                            -> 49808
#define OFF_AJCNT   49808     // int[32*4]                          -> 50320
#define OFF_AJIDX   50320     // int[32*4*128]                      -> 115856
#define OFF_RMAP    148624    // int[128]                           -> 149136
#define OFF_VI      149136    // float[768]                         -> 152208
#define OFF_VJ      152208    // float[768]                         -> 155280
#define OFF_BZD     155280    // float[2]                           -> 155296
#define OFF_YB      155296    // float[128*768] yb=attn@bert_roll   -> 548512
#define OFF_DG      548512    // float[128*64]  D                   -> 581280
#define OFF_YP      581280    // float[4*128*768] y partials        -> 2154144
#define OFF_ZSAP    2154144   // float[4*128*768] zsa partials      -> 3727008
#define OFF_NBRP    3727008   // float[2*128*768] nbr partials      -> 4513440
#define OFF_TEMPP   4513440   // float[4*128*768] temp partials     -> 6086304

// ---------------- KA (stage 1): masks/lists (blk 0-31), vi/vj (32-34), bzd (35) ----------------
__global__ __launch_bounds__(256) void kA(
    const int* __restrict__ adj, const int* __restrict__ asp_s, const int* __restrict__ asp_e,
    const float* __restrict__ Wz, const float* __restrict__ wa, const float* __restrict__ bz,
    int* __restrict__ aspect_slot, int* __restrict__ aspect_idx, int* __restrict__ nasp,
    int* __restrict__ aj_cnt, int* __restrict__ aj_idx, int* __restrict__ row_map,
    float* __restrict__ vi, float* __restrict__ vj, float* __restrict__ bzd) {
  int blk = blockIdx.x, tid = threadIdx.x;
  if (blk < 32) {
    int b = blk;
    __shared__ int asp_flag[128];
    __shared__ int s_aidx[4];
    __shared__ int s_nasp;
    if (tid < 128) {
      const int* arow = adj + ((size_t)(b * 128 + tid)) * 128;
      int any = 0;
      for (int j = 0; j < 128; j += 4) {
        int4 v = *(const int4*)(arow + j);
        any |= v.x | v.y | v.z | v.w;
      }
      int s0 = asp_s[b], e0 = asp_e[b];
      asp_flag[tid] = (tid >= s0 && tid <= e0 && any > 0) ? 1 : 0;
      aspect_slot[b * 128 + tid] = -1;
    }
    __syncthreads();
    if (tid == 0) {
      int n = 0;
      for (int i = 0; i < 128; ++i)
        if (asp_flag[i] && n < 4) s_aidx[n++] = i;
      s_nasp = n;
      nasp[b] = n;
    }
    __syncthreads();
    int na = s_nasp;
    if (tid < 4) row_map[b * 4 + tid] = b * 128;
    if (tid < na) {
      int a = s_aidx[tid];
      aspect_idx[b * 4 + tid] = a;
      aspect_slot[b * 128 + a] = tid;
      row_map[b * 4 + tid] = b * 128 + a;
      int c = 0;
      const int* ar = adj + ((size_t)(b * 128 + a)) * 128;
      for (int j = 0; j < 128; ++j)
        if (ar[j] > 0) aj_idx[(b * 4 + tid) * 128 + (c++)] = j;
      aj_cnt[b * 4 + tid] = c;
    }
  } else if (blk < 35) {
    int k = (blk - 32) * 256 + tid;
    float ai = 0.f, aj = 0.f;
#pragma unroll 8
    for (int h = 0; h < 768; ++h) {
      float w = Wz[(size_t)h * 768 + k];
      ai += w * wa[h];
      aj += w * wa[768 + h];
    }
    vi[k] = ai;
    vj[k] = aj;
  } else {
    if (tid < 64) {
      float bi = 0.f, bj = 0.f;
#pragma unroll
      for (int q = 0; q < 12; ++q) {
        float bv = bz[q * 64 + tid];
        bi += bv * wa[q * 64 + tid];
        bj += bv * wa[768 + q * 64 + tid];
      }
#pragma unroll
      for (int d = 32; d; d >>= 1) { bi += __shfl_xor(bi, d, 64); bj += __shfl_xor(bj, d, 64); }
      if (tid == 0) { bzd[0] = bi; bzd[1] = bj; }
    }
  }
}

// ---------------- KB (stage 2): attn+sij (blk 0-31), zsa partials (32-415), bert copy (416+) ----------------
__global__ __launch_bounds__(256) void kB(
    const float* __restrict__ dep, const float* __restrict__ bert,
    const float* __restrict__ wa, const float* __restrict__ ba,
    const float* __restrict__ vi, const float* __restrict__ vj, const float* __restrict__ bzd,
    const float* __restrict__ Wz, const float* __restrict__ bz,
    const int* __restrict__ nasp, const int* __restrict__ aspect_idx,
    const int* __restrict__ aj_cnt, const int* __restrict__ aj_idx,
    const int* __restrict__ aspect_slot, const int* __restrict__ row_map,
    float* __restrict__ YB, float* __restrict__ DG, float* __restrict__ zsap,
    float* __restrict__ out) {
  int blk = blockIdx.x, tid = threadIdx.x;
  if (blk < 32) {
    // ---- fused s_i/s_j + attention ----
    int b = blk;
    int na = nasp[b];
    if (na == 0) return;
    __shared__ float vis[768];
    __shared__ float vjs[768];
    __shared__ float att[4][128];
    __shared__ float sjs[4][128];
    __shared__ float sis[4];
    __shared__ int jl[4][128];
    __shared__ int aidx[4];
    __shared__ int ajc[4];
    __shared__ float wae[64];
    if (tid < 4) { aidx[tid] = aspect_idx[b * 4 + tid]; ajc[tid] = aj_cnt[b * 4 + tid]; }
    if (tid < 64) wae[tid] = wa[1536 + tid];
    for (int q = tid; q < 512; q += 256) jl[q >> 7][q & 127] = aj_idx[b * 512 + q];
    for (int q = tid; q < 768; q += 256) { vis[q] = vi[q]; vjs[q] = vj[q]; }
    __syncthreads();
    int w = tid >> 6, l = tid & 63;
    float bzd0 = bzd[0], bzd1 = bzd[1];
    // row list per aspect w2: [aspect row, neighbors...]; offs = prefix sums
    int offs[5];
    {
      int o = 0;
      for (int w2 = 0; w2 < 4; ++w2) { offs[w2] = o; if (w2 < na) o += 1 + ajc[w2]; }
      offs[4] = o;
    }
    for (int p = w; p < offs[4]; p += 4) {
      int w2 = 0;
      if (p >= offs[1]) w2 = 1;
      if (p >= offs[2]) w2 = 2;
      if (p >= offs[3]) w2 = 3;
      int idx = p - offs[w2];
      int row = (idx == 0) ? aidx[w2] : jl[w2][idx - 1];
      const float* br = bert + (size_t)(b * 128 + ((row + 1) & 127)) * 768;
      float acc = 0.f;
      if (idx == 0) {
#pragma unroll
        for (int q = 0; q < 12; ++q) acc += br[q * 64 + l] * vis[q * 64 + l];
      } else {
#pragma unroll
        for (int q = 0; q < 12; ++q) acc += br[q * 64 + l] * vjs[q * 64 + l];
      }
#pragma unroll
      for (int d = 32; d; d >>= 1) acc += __shfl_xor(acc, d, 64);
      if (l == 0) {
        if (idx == 0) sis[w2] = acc + bzd0;
        else sjs[w2][idx - 1] = acc + bzd1;
      }
    }
    __syncthreads();
    if (w >= na) return;
    int a = aidx[w], cj = ajc[w];
    float sib = sis[w] + ba[0];
    const float* depa = dep + ((size_t)(b * 128 + a)) * 128 * 64;
    float sc0 = -INFINITY, sc1 = -INFINITY;
    for (int t = l; t < cj; t += 64) {
      int j = jl[w][t];
      const float4* dp = (const float4*)(depa + (size_t)j * 64);
      float se = 0.f;
#pragma unroll
      for (int q = 0; q < 16; ++q) {
        float4 v = dp[q];
        se += v.x * wae[4 * q] + v.y * wae[4 * q + 1] + v.z * wae[4 * q + 2] + v.w * wae[4 * q + 3];
      }
      float sc = sib + sjs[w][t] + se;
      sc = (sc >= 0.f) ? sc : 0.01f * sc;
      if (t < 64) sc0 = sc; else sc1 = sc;
    }
    float mx = fmaxf(sc0, sc1);
#pragma unroll
    for (int d = 32; d; d >>= 1) mx = fmaxf(mx, __shfl_xor(mx, d, 64));
    float p0 = expf(sc0 - mx), p1 = expf(sc1 - mx);
    float sm = p0 + p1;
#pragma unroll
    for (int d = 32; d; d >>= 1) sm += __shfl_xor(sm, d, 64);
    float inv = 1.f / sm;
    if (l < cj) att[w][l] = p0 * inv;
    if (l + 64 < cj) att[w][l + 64] = p1 * inv;
    float y[12];
#pragma unroll
    for (int q = 0; q < 12; ++q) y[q] = 0.f;
    float dacc = 0.f;
    for (int t = 0; t < cj; ++t) {
      float at = att[w][t];
      int j = jl[w][t];
      const float* br = bert + (size_t)(b * 128 + ((j + 1) & 127)) * 768;
#pragma unroll
      for (int q = 0; q < 12; ++q) y[q] += at * br[q * 64 + l];
      dacc += at * depa[(size_t)j * 64 + l];
    }
    float* yr = YB + (size_t)(b * 4 + w) * 768;
#pragma unroll
    for (int q = 0; q < 12; ++q) yr[q * 64 + l] = y[q];
    DG[(b * 4 + w) * 64 + l] = dacc;
  } else if (blk < 416) {
    // ---- zsa partials: idx -> (bx, hc, kc) ----
    int idx = blk - 32;
    int kc = idx & 3, hc = (idx >> 2) % 3, bx = idx / 12;
    int s0 = bx * 4;
    __shared__ float Xs[4][192];
    if (tid < 192) {
      int r = tid / 48, c = tid - r * 48;
      int zrow = row_map[s0 + r];
      int bb = zrow >> 7, ii = zrow & 127;
      const float4* src = (const float4*)(bert + ((size_t)(bb * 128) + ((ii + 1) & 127)) * 768) + kc * 48;
      ((float4*)Xs[r])[c] = src[c];
    }
    __syncthreads();
    int h = hc * 256 + tid;
    const float4* wp = (const float4*)(Wz + (size_t)h * 768) + kc * 48;
    float accA[4] = {};
    float accB[4] = {};
#pragma unroll 6
    for (int k4 = 0; k4 < 24; ++k4) {
      float4 w0 = wp[k4];
      float4 w1 = wp[k4 + 24];
#pragma unroll
      for (int r = 0; r < 4; ++r) {
        float4 x0 = ((const float4*)Xs[r])[k4];
        float4 x1 = ((const float4*)Xs[r])[k4 + 24];
        accA[r] += x0.x * w0.x + x0.y * w0.y + x0.z * w0.z + x0.w * w0.w;
        accB[r] += x1.x * w1.x + x1.y * w1.y + x1.z * w1.z + x1.w * w1.w;
      }
    }
    float bzv = (kc == 0) ? bz[h] : 0.f;
#pragma unroll
    for (int r = 0; r < 4; ++r)
      zsap[((size_t)kc * 128 + s0 + r) * 768 + h] = accA[r] + accB[r] + bzv;
  } else {
    // ---- bulk copy: out = bert for non-updated rows ----
    int idx = (blk - 416) * 256 + tid;  // float4 index over 786432
    int row = idx / 192;
    int b = row >> 7, i = row & 127;
    int slot = (i > 0) ? aspect_slot[b * 128 + i - 1] : -1;
    if (slot < 0) ((float4*)out)[idx] = ((const float4*)bert)[idx];
  }
}

// ---------------- G0: y partials = YB @ Wz^T + bz, K-split by 4 (256 thr) ----------------
__global__ __launch_bounds__(256) void g0_wz(
    const float* __restrict__ YB, const float* __restrict__ Wz, const float* __restrict__ bz,
    float* __restrict__ yp) {
  int s0 = blockIdx.x * 4, hc = blockIdx.y, kc = blockIdx.z;
  int tid = threadIdx.x;
  __shared__ float Xs[4][192];
  if (tid < 192) {
    int r = tid / 48, c = tid - r * 48;
    const float4* src = (const float4*)(YB + (size_t)(s0 + r) * 768) + kc * 48;
    ((float4*)Xs[r])[c] = src[c];
  }
  __syncthreads();
  int h = hc * 256 + tid;
  const float4* wp = (const float4*)(Wz + (size_t)h * 768) + kc * 48;
  float accA[4] = {};
  float accB[4] = {};
#pragma unroll 6
  for (int k4 = 0; k4 < 24; ++k4) {
    float4 w0 = wp[k4];
    float4 w1 = wp[k4 + 24];
#pragma unroll
    for (int r = 0; r < 4; ++r) {
      float4 x0 = ((const float4*)Xs[r])[k4];
      float4 x1 = ((const float4*)Xs[r])[k4 + 24];
      accA[r] += x0.x * w0.x + x0.y * w0.y + x0.z * w0.z + x0.w * w0.w;
      accB[r] += x1.x * w1.x + x1.y * w1.y + x1.z * w1.z + x1.w * w1.w;
    }
  }
  float bzv = (kc == 0) ? bz[h] : 0.f;
#pragma unroll
  for (int r = 0; r < 4; ++r)
    yp[((size_t)kc * 128 + s0 + r) * 768 + h] = accA[r] + accB[r] + bzv;
}

// ---------------- G1: nbr partials = [y|D] @ Wf^T (K=832, 2 chunks) ----------------
__global__ __launch_bounds__(256) void gemv1_wf(
    const float* __restrict__ yp, const float* __restrict__ DG, const float* __restrict__ Wf,
    float* __restrict__ nbr_part) {
  int g = blockIdx.x, nc = blockIdx.y, kc = blockIdx.z;
  int tid = threadIdx.x;
  __shared__ float Xs[4][416];
#pragma unroll
  for (int r = 0; r < 4; ++r) {
    if (tid < 104) {
      int row = g * 4 + r;
      int Q = kc * 104 + tid;
      float4 v;
      if (Q < 192) {
        float4 p0 = *((const float4*)(yp + (size_t)row * 768) + Q);
        float4 p1 = *((const float4*)(yp + ((size_t)128 + row) * 768) + Q);
        float4 p2 = *((const float4*)(yp + ((size_t)256 + row) * 768) + Q);
        float4 p3 = *((const float4*)(yp + ((size_t)384 + row) * 768) + Q);
        v = make_float4(p0.x + p1.x + p2.x + p3.x, p0.y + p1.y + p2.y + p3.y,
                        p0.z + p1.z + p2.z + p3.z, p0.w + p1.w + p2.w + p3.w);
      } else {
        v = *((const float4*)(DG + (size_t)row * 64) + (Q - 192));
      }
      ((float4*)Xs[r])[tid] = v;
    }
  }
  __syncthreads();
  int h = nc * 256 + tid;
  float acc[4] = {};
  const float4* wp = (const float4*)(Wf + (size_t)h * 832 + kc * 416);
#pragma unroll 4
  for (int k4 = 0; k4 < 104; ++k4) {
    float4 wv = wp[k4];
#pragma unroll
    for (int r = 0; r < 4; ++r) {
      float4 xv = ((const float4*)Xs[r])[k4];
      acc[r] += xv.x * wv.x + xv.y * wv.y + xv.z * wv.z + xv.w * wv.w;
    }
  }
#pragma unroll
  for (int r = 0; r < 4; ++r)
    nbr_part[((size_t)kc * 128 + g * 4 + r) * 768 + h] = acc[r];
}

// ---------------- G2: temp partials = [nbr|zsa] @ Wh^T (K=1536, 4 chunks) ----------------
__global__ __launch_bounds__(256) void gemv2_wh(
    const float* __restrict__ nbr_part, const float* __restrict__ zsap,
    const float* __restrict__ Wh, float* __restrict__ temp_part) {
  int g = blockIdx.x, nc = blockIdx.y, kc = blockIdx.z;
  int tid = threadIdx.x;
  __shared__ float Xs[4][384];
  if (kc < 2) {
#pragma unroll
    for (int r = 0; r < 4; ++r) {
      if (tid < 96) {
        int row = g * 4 + r;
        float4 p0 = *((const float4*)(nbr_part + (size_t)row * 768 + kc * 384) + tid);
        float4 p1 = *((const float4*)(nbr_part + ((size_t)128 + row) * 768 + kc * 384) + tid);
        ((float4*)Xs[r])[tid] = make_float4(p0.x + p1.x, p0.y + p1.y, p0.z + p1.z, p0.w + p1.w);
      }
    }
  } else {
#pragma unroll
    for (int r = 0; r < 4; ++r) {
      if (tid < 96) {
        int row = g * 4 + r;
        int Q = (kc - 2) * 96 + tid;
        float4 p0 = *((const float4*)(zsap + (size_t)row * 768) + Q);
        float4 p1 = *((const float4*)(zsap + ((size_t)128 + row) * 768) + Q);
        float4 p2 = *((const float4*)(zsap + ((size_t)256 + row) * 768) + Q);
        float4 p3 = *((const float4*)(zsap + ((size_t)384 + row) * 768) + Q);
        ((float4*)Xs[r])[tid] = make_float4(p0.x + p1.x + p2.x + p3.x, p0.y + p1.y + p2.y + p3.y,
                                            p0.z + p1.z + p2.z + p3.z, p0.w + p1.w + p2.w + p3.w);
      }
    }
  }
  __syncthreads();
  int h = nc * 256 + tid;
  float acc[4] = {};
  const float4* wp = (const float4*)(Wh + (size_t)h * 1536 + kc * 384);
#pragma unroll 4
  for (int k4 = 0; k4 < 96; ++k4) {
    float4 wv = wp[k4];
#pragma unroll
    for (int r = 0; r < 4; ++r) {
      float4 xv = ((const float4*)Xs[r])[k4];
      acc[r] += xv.x * wv.x + xv.y * wv.y + xv.z * wv.z + xv.w * wv.w;
    }
  }
#pragma unroll
  for (int r = 0; r < 4; ++r)
    temp_part[((size_t)kc * 128 + g * 4 + r) * 768 + h] = acc[r];
}

// ---------------- K4b: write only the 128 aspect output rows ----------------
__global__ __launch_bounds__(192) void k4b_out(
    const float* __restrict__ temp_part, const int* __restrict__ row_map,
    const int* __restrict__ nasp, float* __restrict__ out) {
  int g = blockIdx.x;  // b*4+s
  int b = g >> 2, s = g & 3;
  if (s >= nasp[b]) return;
  int tid = threadIdx.x;  // f4 index within row (192)
  int orow = row_map[g] + 1;  // output row = aspect row + 1 (asp_end <= L-2)
  float4 a0 = *((const float4*)(temp_part + (size_t)g * 768) + tid);
  float4 a1 = *((const float4*)(temp_part + ((size_t)128 + g) * 768) + tid);
  float4 a2 = *((const float4*)(temp_part + ((size_t)256 + g) * 768) + tid);
  float4 a3 = *((const float4*)(temp_part + ((size_t)384 + g) * 768) + tid);
  ((float4*)out)[(size_t)orow * 192 + tid] =
      make_float4(a0.x + a1.x + a2.x + a3.x, a0.y + a1.y + a2.y + a3.y,
                  a0.z + a1.z + a2.z + a3.z, a0.w + a1.w + a2.w + a3.w);
}

extern "C" void kernel_launch(void* const* d_in, const int* in_sizes, int n_in,
                              void* d_out, int out_size, void* d_ws, size_t ws_size,
                              hipStream_t stream) {
  const float* bert = (const float*)d_in[0];
  const float* dep  = (const float*)d_in[1];
  const int*   adj  = (const int*)d_in[2];
  const int*   asps = (const int*)d_in[3];
  const int*   aspe = (const int*)d_in[4];
  const float* Wz   = (const float*)d_in[5];
  const float* bz   = (const float*)d_in[6];
  const float* wa   = (const float*)d_in[7];
  const float* ba   = (const float*)d_in[8];
  const float* Wf   = (const float*)d_in[9];
  const float* Wh   = (const float*)d_in[10];
  float* out = (float*)d_out;
  char* ws = (char*)d_ws;

  int*   aspect_slot = (int*)(ws + OFF_ASLOT);
  int*   aspect_idx  = (int*)(ws + OFF_AIDX);
  int*   nasp        = (int*)(ws + OFF_NASP);
  int*   aj_cnt      = (int*)(ws + OFF_AJCNT);
  int*   aj_idx      = (int*)(ws + OFF_AJIDX);
  int*   row_map     = (int*)(ws + OFF_RMAP);
  float* vi          = (float*)(ws + OFF_VI);
  float* vj          = (float*)(ws + OFF_VJ);
  float* bzd         = (float*)(ws + OFF_BZD);
  float* YB          = (float*)(ws + OFF_YB);
  float* DG          = (float*)(ws + OFF_DG);
  float* yp          = (float*)(ws + OFF_YP);
  float* zsap        = (float*)(ws + OFF_ZSAP);
  float* nbr_part    = (float*)(ws + OFF_NBRP);
  float* temp_part   = (float*)(ws + OFF_TEMPP);

  kA<<<36, 256, 0, stream>>>(adj, asps, aspe, Wz, wa, bz,
                             aspect_slot, aspect_idx, nasp, aj_cnt, aj_idx, row_map,
                             vi, vj, bzd);
  kB<<<3488, 256, 0, stream>>>(dep, bert, wa, ba, vi, vj, bzd, Wz, bz,
                               nasp, aspect_idx, aj_cnt, aj_idx, aspect_slot, row_map,
                               YB, DG, zsap, out);
  g0_wz<<<dim3(32, 3, 4), 256, 0, stream>>>(YB, Wz, bz, yp);
  gemv1_wf<<<dim3(32, 3, 2), 256, 0, stream>>>(yp, DG, Wf, nbr_part);
  gemv2_wh<<<dim3(32, 3, 4), 256, 0, stream>>>(nbr_part, zsap, Wh, temp_part);
  k4b_out<<<128, 192, 0, stream>>>(temp_part, row_map, nasp, out);
}